// Round 11
// baseline (99.845 us; speedup 1.0000x reference)
//
#include <hip/hip_runtime.h>
#include <hip/hip_cooperative_groups.h>
#include <math.h>

namespace cg = cooperative_groups;

#define NB 65536          // batch
#define NTILES 2048       // 32-image tiles
#define IMGS1 32          // images per tile (8 threads/image, 3 rows each)

// ---------------------------------------------------------------------------
// Shared device helpers (same math as R9, verified)
// ---------------------------------------------------------------------------
__device__ __forceinline__ void build_W_lane(int t, const float* __restrict__ weights,
                                             float2* __restrict__ Wl) {
    float cr[16], ci[16];
#pragma unroll
    for (int i = 0; i < 16; ++i) { cr[i] = (i == t) ? 1.0f : 0.0f; ci[i] = 0.0f; }

    for (int l = 0; l < 3; ++l) {
#pragma unroll
        for (int w = 0; w < 4; ++w) {
            const int mask = 8 >> w;            // wire w -> bit (3-w)
            float tx = weights[(l * 4 + w) * 2 + 0] * 0.5f;
            float c = cosf(tx), s = sinf(tx);
#pragma unroll
            for (int i = 0; i < 16; ++i) {
                if (!(i & mask)) {
                    const int ip = i | mask;
                    float a0r = cr[i], a0i = ci[i], a1r = cr[ip], a1i = ci[ip];
                    cr[i]  = c * a0r + s * a1i;   // [[c,-is],[-is,c]]
                    ci[i]  = c * a0i - s * a1r;
                    cr[ip] = c * a1r + s * a0i;
                    ci[ip] = c * a1i - s * a0r;
                }
            }
            float tz = weights[(l * 4 + w) * 2 + 1] * 0.5f;
            float ce = cosf(tz), se = sinf(tz);
#pragma unroll
            for (int i = 0; i < 16; ++i) {
                if (!(i & mask)) {
                    const int ip = i | mask;
                    float a0r = cr[i], a0i = ci[i], a1r = cr[ip], a1i = ci[ip];
                    cr[i]  = ce * a0r + se * a0i;  // e^{-i tz}
                    ci[i]  = ce * a0i - se * a0r;
                    cr[ip] = ce * a1r - se * a1i;  // e^{+i tz}
                    ci[ip] = ce * a1i + se * a1r;
                }
            }
        }
#pragma unroll
        for (int w = 0; w < 4; ++w) {           // CNOT ring
            const int mc = 8 >> w;
            const int mt = 8 >> ((w + 1) & 3);
#pragma unroll
            for (int i = 0; i < 16; ++i) {
                if ((i & mc) && !(i & mt)) {
                    const int ip = i | mt;
                    float tr = cr[i], ti = ci[i];
                    cr[i] = cr[ip]; ci[i] = ci[ip];
                    cr[ip] = tr;   ci[ip] = ti;
                }
            }
        }
    }
    int p = __popc(t) & 3;   // fold zeta_j = (-i)^popcount(j)
#pragma unroll
    for (int i = 0; i < 16; ++i) {
        float wr, wi;
        if (p == 0)      { wr =  cr[i]; wi =  ci[i]; }
        else if (p == 1) { wr =  ci[i]; wi = -cr[i]; }
        else if (p == 2) { wr = -cr[i]; wi = -ci[i]; }
        else             { wr = -ci[i]; wi =  cr[i]; }
        Wl[i * 16 + t] = make_float2(wr, wi);
    }
}

// pool + pre-FC partial for one thread (8 threads/image, 3 rows each);
// returns the 4 pre-FC partials (to be combined over the 8-lane group).
__device__ __forceinline__ float4 pool_prefc(const float* __restrict__ img,
                                             const float* __restrict__ pre_w,
                                             int t8) {
    float cs0 = 0.f, cs1 = 0.f, cs2 = 0.f, cs3 = 0.f;
#pragma unroll
    for (int r = 0; r < 3; ++r) {
        const float4* row = (const float4*)(img + r * 28);  // 16B-aligned
        float4 f0 = row[0], f1 = row[1], f2 = row[2];
        float4 f3 = row[3], f4 = row[4], f5 = row[5];
        cs0 += f0.x + f0.y + f0.z + f0.w + f1.x + f1.y;   // cols 0..5
        cs1 += f1.z + f1.w + f2.x + f2.y + f2.z + f2.w;   // cols 6..11
        cs2 += f3.x + f3.y + f3.z + f3.w + f4.x + f4.y;   // cols 12..17
        cs3 += f4.z + f4.w + f5.x + f5.y + f5.z + f5.w;   // cols 18..23
    }
    const float inv36 = 1.0f / 36.0f;
    cs0 *= inv36; cs1 *= inv36; cs2 *= inv36; cs3 *= inv36;

    const int k0 = (t8 >> 1) * 4;
    float4 p;
    p.x = cs0 * pre_w[k0]      + cs1 * pre_w[k0 + 1] +
          cs2 * pre_w[k0 + 2]  + cs3 * pre_w[k0 + 3];
    p.y = cs0 * pre_w[16 + k0] + cs1 * pre_w[16 + k0 + 1] +
          cs2 * pre_w[16 + k0 + 2] + cs3 * pre_w[16 + k0 + 3];
    p.z = cs0 * pre_w[32 + k0] + cs1 * pre_w[32 + k0 + 1] +
          cs2 * pre_w[32 + k0 + 2] + cs3 * pre_w[32 + k0 + 3];
    p.w = cs0 * pre_w[48 + k0] + cs1 * pre_w[48 + k0 + 1] +
          cs2 * pre_w[48 + k0 + 2] + cs3 * pre_w[48 + k0 + 3];
    return p;
}

// quantum matvec + logits for one image (one lane)
__device__ __forceinline__ float4 quantum_logits(float4 e,
                                                 const float2* __restrict__ Wl,
                                                 const float* __restrict__ fc_w,
                                                 const float* __restrict__ fc_b) {
    float s0, c0, s1, c1, s2, c2, s3, c3;
    __sincosf(e.x * 0.5f, &s0, &c0);
    __sincosf(e.y * 0.5f, &s1, &c1);
    __sincosf(e.z * 0.5f, &s2, &c2);
    __sincosf(e.w * 0.5f, &s3, &c3);

    float m01[4] = { c0 * c1, c0 * s1, s0 * c1, s0 * s1 };
    float m23[4] = { c2 * c3, c2 * s3, s2 * c3, s2 * s3 };
    float m[16];
#pragma unroll
    for (int i = 0; i < 16; ++i) m[i] = m01[i >> 2] * m23[i & 3];

    float z0 = 0.f, z1 = 0.f, z2 = 0.f, z3 = 0.f;
#pragma unroll
    for (int i = 0; i < 16; ++i) {
        float sr = 0.f, si = 0.f;
#pragma unroll
        for (int j = 0; j < 16; ++j) {
            float2 w = Wl[i * 16 + j];   // wave-uniform -> LDS broadcast
            sr += w.x * m[j];
            si += w.y * m[j];
        }
        float pr = sr * sr + si * si;
        z0 += (i & 8) ? -pr : pr;
        z1 += (i & 4) ? -pr : pr;
        z2 += (i & 2) ? -pr : pr;
        z3 += (i & 1) ? -pr : pr;
    }
    float4 l;
    l.x = fc_b[0] + fc_w[0]  * z0 + fc_w[1]  * z1 + fc_w[2]  * z2 + fc_w[3]  * z3;
    l.y = fc_b[1] + fc_w[4]  * z0 + fc_w[5]  * z1 + fc_w[6]  * z2 + fc_w[7]  * z3;
    l.z = fc_b[2] + fc_w[8]  * z0 + fc_w[9]  * z1 + fc_w[10] * z2 + fc_w[11] * z3;
    l.w = fc_b[3] + fc_w[12] * z0 + fc_w[13] * z1 + fc_w[14] * z2 + fc_w[15] * z3;
    return l;
}

// ---------------------------------------------------------------------------
// Single cooperative kernel: grid-stride over 2048 tiles (R9 pool+quantum),
// register BN accumulation, grid.sync, redundant partial reduce, normalize
// own tiles in place. Grid sized by occupancy query at launch.
// ---------------------------------------------------------------------------
__global__ __launch_bounds__(256) void fused_all(
        const float* __restrict__ x,
        const float* __restrict__ pre_w,
        const float* __restrict__ pre_b,
        const float* __restrict__ weights,
        const float* __restrict__ fc_w,
        const float* __restrict__ fc_b,
        const float* __restrict__ gamma,
        const float* __restrict__ beta,
        float4* __restrict__ out,
        float* __restrict__ partial,
        int ntiles) {
    __shared__ float2 Wl[256];
    __shared__ float4 enc[2][IMGS1];
    __shared__ float red4[4][8];
    __shared__ float scsh[8];
    const int tid = threadIdx.x;

    if (tid >= 192 && tid < 208) build_W_lane(tid - 192, weights, Wl);

    const int t8 = tid & 7;
    const int imgInTile = tid >> 3;
    float a0 = 0.f, a1 = 0.f, a2 = 0.f, a3 = 0.f;
    float a4 = 0.f, a5 = 0.f, a6 = 0.f, a7 = 0.f;   // tid0's BN accum

    int k = 0;
    for (int tile = blockIdx.x; tile < ntiles; tile += gridDim.x, ++k) {
        const size_t img_idx = (size_t)tile * IMGS1 + imgInTile;
        float4 p = pool_prefc(x + img_idx * 784 + (size_t)(t8 * 3) * 28,
                              pre_w, t8);
        p.x += __shfl_xor(p.x, 1); p.x += __shfl_xor(p.x, 2); p.x += __shfl_xor(p.x, 4);
        p.y += __shfl_xor(p.y, 1); p.y += __shfl_xor(p.y, 2); p.y += __shfl_xor(p.y, 4);
        p.z += __shfl_xor(p.z, 1); p.z += __shfl_xor(p.z, 2); p.z += __shfl_xor(p.z, 4);
        p.w += __shfl_xor(p.w, 1); p.w += __shfl_xor(p.w, 2); p.w += __shfl_xor(p.w, 4);
        if (t8 == 0) {
            enc[k & 1][imgInTile] = make_float4(p.x + pre_b[0], p.y + pre_b[1],
                                                p.z + pre_b[2], p.w + pre_b[3]);
        }
        __syncthreads();

        if (tid < IMGS1) {
            float4 l = quantum_logits(enc[k & 1][tid], Wl, fc_w, fc_b);
            out[(size_t)tile * IMGS1 + tid] = l;

            float s[8] = { l.x, l.y, l.z, l.w,
                           l.x * l.x, l.y * l.y, l.z * l.z, l.w * l.w };
#pragma unroll
            for (int off = 16; off; off >>= 1) {
#pragma unroll
                for (int q = 0; q < 8; ++q) s[q] += __shfl_down(s[q], off);
            }
            if (tid == 0) {
                a0 += s[0]; a1 += s[1]; a2 += s[2]; a3 += s[3];
                a4 += s[4]; a5 += s[5]; a6 += s[6]; a7 += s[7];
            }
        }
        // next iteration writes enc[(k+1)&1]; readers of enc[k&1] finish
        // before iteration k+1's barrier -> safe without a second barrier.
    }

    if (tid == 0) {
        float4* p = (float4*)(partial + (size_t)blockIdx.x * 8);
        p[0] = make_float4(a0, a1, a2, a3);
        p[1] = make_float4(a4, a5, a6, a7);
    }

    cg::this_grid().sync();

    // redundant reduce of gridDim.x x 8 partials (L2-resident)
    float s[8];
#pragma unroll
    for (int q = 0; q < 8; ++q) s[q] = 0.f;
    for (int r = tid; r < (int)gridDim.x; r += 256) {
        const float4* row = (const float4*)(partial + (size_t)r * 8);
        float4 a = row[0], c = row[1];
        s[0] += a.x; s[1] += a.y; s[2] += a.z; s[3] += a.w;
        s[4] += c.x; s[5] += c.y; s[6] += c.z; s[7] += c.w;
    }
#pragma unroll
    for (int off = 32; off; off >>= 1) {
#pragma unroll
        for (int q = 0; q < 8; ++q) s[q] += __shfl_down(s[q], off);
    }
    if ((tid & 63) == 0) {
#pragma unroll
        for (int q = 0; q < 8; ++q) red4[tid >> 6][q] = s[q];
    }
    __syncthreads();
    if (tid < 8) {
        red4[0][tid] = red4[0][tid] + red4[1][tid] + red4[2][tid] + red4[3][tid];
    }
    __syncthreads();
    if (tid < 4) {
        const float invB = 1.0f / (float)NB;
        float mean = red4[0][tid] * invB;
        float var  = red4[0][4 + tid] * invB - mean * mean;
        float inv  = rsqrtf(var + 1e-5f);
        float g = gamma[tid];
        scsh[tid]     = g * inv;
        scsh[4 + tid] = beta[tid] - mean * g * inv;
    }
    __syncthreads();

    const float sc0 = scsh[0], sc1 = scsh[1], sc2 = scsh[2], sc3 = scsh[3];
    const float sh0 = scsh[4], sh1 = scsh[5], sh2 = scsh[6], sh3 = scsh[7];

    // normalize OWN tiles in place (reads this block's own writes)
    for (int tile = blockIdx.x; tile < ntiles; tile += gridDim.x) {
        if (tid < IMGS1) {
            float4 v = out[(size_t)tile * IMGS1 + tid];
            v.x = v.x * sc0 + sh0;
            v.y = v.y * sc1 + sh1;
            v.z = v.z * sc2 + sh2;
            v.w = v.w * sc3 + sh3;
            out[(size_t)tile * IMGS1 + tid] = v;
        }
    }
}

// ---------------------------------------------------------------------------
// Fallback path (R9, proven 41.4 us): fused + finalize
// ---------------------------------------------------------------------------
__global__ __launch_bounds__(256) void fused_kernel(
        const float* __restrict__ x, const float* __restrict__ pre_w,
        const float* __restrict__ pre_b, const float* __restrict__ weights,
        const float* __restrict__ fc_w, const float* __restrict__ fc_b,
        float4* __restrict__ out, float* __restrict__ partial) {
    __shared__ float2 Wl[256];
    __shared__ float4 enc[IMGS1];
    const int tid = threadIdx.x;

    if (tid >= 192 && tid < 208) build_W_lane(tid - 192, weights, Wl);

    const int t8 = tid & 7;
    const size_t img_idx = (size_t)blockIdx.x * IMGS1 + (tid >> 3);
    float4 p = pool_prefc(x + img_idx * 784 + (size_t)(t8 * 3) * 28, pre_w, t8);
    p.x += __shfl_xor(p.x, 1); p.x += __shfl_xor(p.x, 2); p.x += __shfl_xor(p.x, 4);
    p.y += __shfl_xor(p.y, 1); p.y += __shfl_xor(p.y, 2); p.y += __shfl_xor(p.y, 4);
    p.z += __shfl_xor(p.z, 1); p.z += __shfl_xor(p.z, 2); p.z += __shfl_xor(p.z, 4);
    p.w += __shfl_xor(p.w, 1); p.w += __shfl_xor(p.w, 2); p.w += __shfl_xor(p.w, 4);
    if (t8 == 0) {
        enc[tid >> 3] = make_float4(p.x + pre_b[0], p.y + pre_b[1],
                                    p.z + pre_b[2], p.w + pre_b[3]);
    }
    __syncthreads();

    if (tid < IMGS1) {
        float4 l = quantum_logits(enc[tid], Wl, fc_w, fc_b);
        out[(size_t)blockIdx.x * IMGS1 + tid] = l;
        float s[8] = { l.x, l.y, l.z, l.w,
                       l.x * l.x, l.y * l.y, l.z * l.z, l.w * l.w };
#pragma unroll
        for (int off = 16; off; off >>= 1) {
#pragma unroll
            for (int q = 0; q < 8; ++q) s[q] += __shfl_down(s[q], off);
        }
        if (tid == 0) {
            float4* pp = (float4*)(partial + (size_t)blockIdx.x * 8);
            pp[0] = make_float4(s[0], s[1], s[2], s[3]);
            pp[1] = make_float4(s[4], s[5], s[6], s[7]);
        }
    }
}

__global__ __launch_bounds__(256) void finalize_kernel(
        float4* __restrict__ out, const float* __restrict__ partial,
        const float* __restrict__ gamma, const float* __restrict__ beta) {
    __shared__ float red4[4][8];
    __shared__ float scsh[8];
    const int tid = threadIdx.x;

    float s[8];
#pragma unroll
    for (int q = 0; q < 8; ++q) s[q] = 0.f;
#pragma unroll
    for (int r = 0; r < NTILES / 256; ++r) {
        const float4* row = (const float4*)(partial + (size_t)(tid + r * 256) * 8);
        float4 a = row[0], c = row[1];
        s[0] += a.x; s[1] += a.y; s[2] += a.z; s[3] += a.w;
        s[4] += c.x; s[5] += c.y; s[6] += c.z; s[7] += c.w;
    }
#pragma unroll
    for (int off = 32; off; off >>= 1) {
#pragma unroll
        for (int q = 0; q < 8; ++q) s[q] += __shfl_down(s[q], off);
    }
    if ((tid & 63) == 0) {
#pragma unroll
        for (int q = 0; q < 8; ++q) red4[tid >> 6][q] = s[q];
    }
    __syncthreads();
    if (tid < 8) {
        red4[0][tid] = red4[0][tid] + red4[1][tid] + red4[2][tid] + red4[3][tid];
    }
    __syncthreads();
    if (tid < 4) {
        const float invB = 1.0f / (float)NB;
        float mean = red4[0][tid] * invB;
        float var  = red4[0][4 + tid] * invB - mean * mean;
        float inv  = rsqrtf(var + 1e-5f);
        float g = gamma[tid];
        scsh[tid]     = g * inv;
        scsh[4 + tid] = beta[tid] - mean * g * inv;
    }
    __syncthreads();

    const float sc0 = scsh[0], sc1 = scsh[1], sc2 = scsh[2], sc3 = scsh[3];
    const float sh0 = scsh[4], sh1 = scsh[5], sh2 = scsh[6], sh3 = scsh[7];
    const int b = blockIdx.x * 256 + tid;
    float4 v = out[b];
    v.x = v.x * sc0 + sh0;
    v.y = v.y * sc1 + sh1;
    v.z = v.z * sc2 + sh2;
    v.w = v.w * sc3 + sh3;
    out[b] = v;
}

// ---------------------------------------------------------------------------
extern "C" void kernel_launch(void* const* d_in, const int* in_sizes, int n_in,
                              void* d_out, int out_size, void* d_ws, size_t ws_size,
                              hipStream_t stream) {
    const float* x       = (const float*)d_in[0];
    const float* pre_w   = (const float*)d_in[1];
    const float* pre_b   = (const float*)d_in[2];
    const float* weights = (const float*)d_in[3];
    const float* fc_w    = (const float*)d_in[4];
    const float* fc_b    = (const float*)d_in[5];
    const float* gamma   = (const float*)d_in[6];
    const float* beta    = (const float*)d_in[7];

    float4* out4   = (float4*)d_out;
    float* partial = (float*)d_ws;           // <= 2048*8*4 = 64 KB

    // size cooperative grid from the occupancy query (legal by construction)
    int occ = 0;
    hipError_t qe = hipOccupancyMaxActiveBlocksPerMultiprocessor(
        &occ, (const void*)fused_all, 256, 0);
    if (qe == hipSuccess && occ > 0) {
        int nblk = occ * 256;                // 256 CUs on MI355X
        if (nblk > NTILES) nblk = NTILES;
        int ntiles = NTILES;
        void* args[] = {
            (void*)&x, (void*)&pre_w, (void*)&pre_b, (void*)&weights,
            (void*)&fc_w, (void*)&fc_b, (void*)&gamma, (void*)&beta,
            (void*)&out4, (void*)&partial, (void*)&ntiles
        };
        if (hipLaunchCooperativeKernel((const void*)fused_all, dim3(nblk),
                                       dim3(256), args, 0, stream) == hipSuccess) {
            return;
        }
    }

    // fallback: proven two-kernel path (R9)
    hipLaunchKernelGGL(fused_kernel, dim3(NTILES), dim3(256), 0, stream,
                       x, pre_w, pre_b, weights, fc_w, fc_b, out4, partial);
    hipLaunchKernelGGL(finalize_kernel, dim3(NB / 256), dim3(256), 0, stream,
                       out4, partial, gamma, beta);
}

// Round 12
// 41.570 us; speedup vs baseline: 2.4019x; 2.4019x over previous
//
#include <hip/hip_runtime.h>
#include <math.h>

#define NB 65536          // batch
#define NBLK1 2048        // fused grid: NB / IMGS1 (full-occupancy grid)
#define IMGS1 32          // images per block (8 threads/image, 3 rows each)

// ---------------------------------------------------------------------------
// Fused kernel (R9, proven 41.4 us): W-build (wave 3 lanes 0-15) + avg-pool
// 6x6 + pre-FC + quantum matvec + logits + per-block BN partials.
// 2048 blocks x 256 threads; no launch_bounds min-waves clause (R5 lesson:
// forcing a 64-VGPR cap spills the pool live set).
// ---------------------------------------------------------------------------
__global__ __launch_bounds__(256) void fused_kernel(
        const float* __restrict__ x,        // [B][1][28][28]
        const float* __restrict__ pre_w,    // [4][16]
        const float* __restrict__ pre_b,    // [4]
        const float* __restrict__ weights,  // [3][4][2]
        const float* __restrict__ fc_w,     // [4][4]
        const float* __restrict__ fc_b,     // [4]
        float4* __restrict__ out,           // [B] raw logits
        float* __restrict__ partial) {      // [NBLK1][8]
    __shared__ float2 Wl[256];
    __shared__ float4 enc[IMGS1];
    const int tid = threadIdx.x;

    // ---------------- build W on wave 3 lanes 0-15 -------------------------
    // (hidden under waves 0-2's pool loads; needed only after the barrier)
    if (tid >= 192 && tid < 208) {
        const int t = tid - 192;
        float cr[16], ci[16];
#pragma unroll
        for (int i = 0; i < 16; ++i) { cr[i] = (i == t) ? 1.0f : 0.0f; ci[i] = 0.0f; }

        for (int l = 0; l < 3; ++l) {
#pragma unroll
            for (int w = 0; w < 4; ++w) {
                const int mask = 8 >> w;            // wire w -> bit (3-w)
                float tx = weights[(l * 4 + w) * 2 + 0] * 0.5f;
                float c = cosf(tx), s = sinf(tx);
#pragma unroll
                for (int i = 0; i < 16; ++i) {
                    if (!(i & mask)) {
                        const int ip = i | mask;
                        float a0r = cr[i], a0i = ci[i], a1r = cr[ip], a1i = ci[ip];
                        cr[i]  = c * a0r + s * a1i;   // [[c,-is],[-is,c]]
                        ci[i]  = c * a0i - s * a1r;
                        cr[ip] = c * a1r + s * a0i;
                        ci[ip] = c * a1i - s * a0r;
                    }
                }
                float tz = weights[(l * 4 + w) * 2 + 1] * 0.5f;
                float ce = cosf(tz), se = sinf(tz);
#pragma unroll
                for (int i = 0; i < 16; ++i) {
                    if (!(i & mask)) {
                        const int ip = i | mask;
                        float a0r = cr[i], a0i = ci[i], a1r = cr[ip], a1i = ci[ip];
                        cr[i]  = ce * a0r + se * a0i;  // e^{-i tz}
                        ci[i]  = ce * a0i - se * a0r;
                        cr[ip] = ce * a1r - se * a1i;  // e^{+i tz}
                        ci[ip] = ce * a1i + se * a1r;
                    }
                }
            }
#pragma unroll
            for (int w = 0; w < 4; ++w) {           // CNOT ring
                const int mc = 8 >> w;
                const int mt = 8 >> ((w + 1) & 3);
#pragma unroll
                for (int i = 0; i < 16; ++i) {
                    if ((i & mc) && !(i & mt)) {
                        const int ip = i | mt;
                        float tr = cr[i], ti = ci[i];
                        cr[i] = cr[ip]; ci[i] = ci[ip];
                        cr[ip] = tr;   ci[ip] = ti;
                    }
                }
            }
        }
        int p = __popc(t) & 3;   // fold zeta_j = (-i)^popcount(j)
#pragma unroll
        for (int i = 0; i < 16; ++i) {
            float wr, wi;
            if (p == 0)      { wr =  cr[i]; wi =  ci[i]; }
            else if (p == 1) { wr =  ci[i]; wi = -cr[i]; }
            else if (p == 2) { wr = -cr[i]; wi = -ci[i]; }
            else             { wr = -ci[i]; wi =  cr[i]; }
            Wl[i * 16 + t] = make_float2(wr, wi);
        }
    }

    // ---------------- pool + pre-FC (8 threads/image, 3 rows each) ---------
    const int t8 = tid & 7;                         // row-band 3*t8..3*t8+2
    const size_t img_idx = (size_t)blockIdx.x * IMGS1 + (tid >> 3);
    const float* img = x + img_idx * 784 + (size_t)(t8 * 3) * 28;

    float cs0 = 0.f, cs1 = 0.f, cs2 = 0.f, cs3 = 0.f;
#pragma unroll
    for (int r = 0; r < 3; ++r) {
        const float4* row = (const float4*)(img + r * 28);  // 16B-aligned
        float4 f0 = row[0], f1 = row[1], f2 = row[2];
        float4 f3 = row[3], f4 = row[4], f5 = row[5];
        cs0 += f0.x + f0.y + f0.z + f0.w + f1.x + f1.y;   // cols 0..5
        cs1 += f1.z + f1.w + f2.x + f2.y + f2.z + f2.w;   // cols 6..11
        cs2 += f3.x + f3.y + f3.z + f3.w + f4.x + f4.y;   // cols 12..17
        cs3 += f4.z + f4.w + f5.x + f5.y + f5.z + f5.w;   // cols 18..23
    }
    const float inv36 = 1.0f / 36.0f;
    cs0 *= inv36; cs1 *= inv36; cs2 *= inv36; cs3 *= inv36;

    // pre-FC partials (weights loaded post-pool; k0 = 4 * vertical band)
    const int k0 = (t8 >> 1) * 4;
    float p0 = cs0 * pre_w[k0]      + cs1 * pre_w[k0 + 1] +
               cs2 * pre_w[k0 + 2]  + cs3 * pre_w[k0 + 3];
    float p1 = cs0 * pre_w[16 + k0] + cs1 * pre_w[16 + k0 + 1] +
               cs2 * pre_w[16 + k0 + 2] + cs3 * pre_w[16 + k0 + 3];
    float p2 = cs0 * pre_w[32 + k0] + cs1 * pre_w[32 + k0 + 1] +
               cs2 * pre_w[32 + k0 + 2] + cs3 * pre_w[32 + k0 + 3];
    float p3 = cs0 * pre_w[48 + k0] + cs1 * pre_w[48 + k0 + 1] +
               cs2 * pre_w[48 + k0 + 2] + cs3 * pre_w[48 + k0 + 3];

    // combine the 8 row-bands of one image (8-lane group)
    p0 += __shfl_xor(p0, 1); p0 += __shfl_xor(p0, 2); p0 += __shfl_xor(p0, 4);
    p1 += __shfl_xor(p1, 1); p1 += __shfl_xor(p1, 2); p1 += __shfl_xor(p1, 4);
    p2 += __shfl_xor(p2, 1); p2 += __shfl_xor(p2, 2); p2 += __shfl_xor(p2, 4);
    p3 += __shfl_xor(p3, 1); p3 += __shfl_xor(p3, 2); p3 += __shfl_xor(p3, 4);

    if (t8 == 0) {
        enc[tid >> 3] = make_float4(p0 + pre_b[0], p1 + pre_b[1],
                                    p2 + pre_b[2], p3 + pre_b[3]);
    }
    __syncthreads();

    // ---------------- quantum matvec + logits (lanes 0-31 of wave 0) -------
    if (tid < IMGS1) {
        float4 e = enc[tid];
        float s0, c0, s1, c1, s2, c2, s3, c3;
        __sincosf(e.x * 0.5f, &s0, &c0);
        __sincosf(e.y * 0.5f, &s1, &c1);
        __sincosf(e.z * 0.5f, &s2, &c2);
        __sincosf(e.w * 0.5f, &s3, &c3);

        float m01[4] = { c0 * c1, c0 * s1, s0 * c1, s0 * s1 };
        float m23[4] = { c2 * c3, c2 * s3, s2 * c3, s2 * s3 };
        float m[16];
#pragma unroll
        for (int i = 0; i < 16; ++i) m[i] = m01[i >> 2] * m23[i & 3];

        float z0 = 0.f, z1 = 0.f, z2 = 0.f, z3 = 0.f;
#pragma unroll
        for (int i = 0; i < 16; ++i) {
            float sr = 0.f, si = 0.f;
#pragma unroll
            for (int j = 0; j < 16; ++j) {
                float2 w = Wl[i * 16 + j];   // wave-uniform -> LDS broadcast
                sr += w.x * m[j];
                si += w.y * m[j];
            }
            float pr = sr * sr + si * si;
            z0 += (i & 8) ? -pr : pr;
            z1 += (i & 4) ? -pr : pr;
            z2 += (i & 2) ? -pr : pr;
            z3 += (i & 1) ? -pr : pr;
        }

        float l0 = fc_b[0] + fc_w[0]  * z0 + fc_w[1]  * z1 + fc_w[2]  * z2 + fc_w[3]  * z3;
        float l1 = fc_b[1] + fc_w[4]  * z0 + fc_w[5]  * z1 + fc_w[6]  * z2 + fc_w[7]  * z3;
        float l2 = fc_b[2] + fc_w[8]  * z0 + fc_w[9]  * z1 + fc_w[10] * z2 + fc_w[11] * z3;
        float l3 = fc_b[3] + fc_w[12] * z0 + fc_w[13] * z1 + fc_w[14] * z2 + fc_w[15] * z3;
        out[(size_t)blockIdx.x * IMGS1 + tid] = make_float4(l0, l1, l2, l3);

        // BN partials over the 32 images (lanes 0-31)
        float s[8] = { l0, l1, l2, l3, l0 * l0, l1 * l1, l2 * l2, l3 * l3 };
#pragma unroll
        for (int off = 16; off; off >>= 1) {
#pragma unroll
            for (int q = 0; q < 8; ++q) s[q] += __shfl_down(s[q], off);
        }
        if (tid == 0) {
            float4* p = (float4*)(partial + (size_t)blockIdx.x * 8);
            p[0] = make_float4(s[0], s[1], s[2], s[3]);
            p[1] = make_float4(s[4], s[5], s[6], s[7]);
        }
    }
}

// ---------------------------------------------------------------------------
// Finalize: each of 256 blocks redundantly reduces the 2048x8 partials
// (L2-hit), computes scale/shift, normalizes its 256 images in place.
// ---------------------------------------------------------------------------
__global__ __launch_bounds__(256) void finalize_kernel(
        float4* __restrict__ out,
        const float* __restrict__ partial,   // [NBLK1][8]
        const float* __restrict__ gamma,
        const float* __restrict__ beta) {
    __shared__ float red4[4][8];
    __shared__ float scsh[8];
    const int tid = threadIdx.x;

    float s[8];
#pragma unroll
    for (int q = 0; q < 8; ++q) s[q] = 0.f;
#pragma unroll
    for (int r = 0; r < NBLK1 / 256; ++r) {
        const float4* row = (const float4*)(partial + (size_t)(tid + r * 256) * 8);
        float4 a = row[0], c = row[1];
        s[0] += a.x; s[1] += a.y; s[2] += a.z; s[3] += a.w;
        s[4] += c.x; s[5] += c.y; s[6] += c.z; s[7] += c.w;
    }
#pragma unroll
    for (int off = 32; off; off >>= 1) {
#pragma unroll
        for (int q = 0; q < 8; ++q) s[q] += __shfl_down(s[q], off);
    }
    if ((tid & 63) == 0) {
#pragma unroll
        for (int q = 0; q < 8; ++q) red4[tid >> 6][q] = s[q];
    }
    __syncthreads();
    if (tid < 8) {
        red4[0][tid] = red4[0][tid] + red4[1][tid] + red4[2][tid] + red4[3][tid];
    }
    __syncthreads();
    if (tid < 4) {
        const float invB = 1.0f / (float)NB;
        float mean = red4[0][tid] * invB;
        float var  = red4[0][4 + tid] * invB - mean * mean;
        float inv  = rsqrtf(var + 1e-5f);
        float g = gamma[tid];
        scsh[tid]     = g * inv;
        scsh[4 + tid] = beta[tid] - mean * g * inv;
    }
    __syncthreads();

    const float sc0 = scsh[0], sc1 = scsh[1], sc2 = scsh[2], sc3 = scsh[3];
    const float sh0 = scsh[4], sh1 = scsh[5], sh2 = scsh[6], sh3 = scsh[7];
    const int b = blockIdx.x * 256 + tid;    // 256 blocks cover NB
    float4 v = out[b];
    v.x = v.x * sc0 + sh0;
    v.y = v.y * sc1 + sh1;
    v.z = v.z * sc2 + sh2;
    v.w = v.w * sc3 + sh3;
    out[b] = v;
}

// ---------------------------------------------------------------------------
extern "C" void kernel_launch(void* const* d_in, const int* in_sizes, int n_in,
                              void* d_out, int out_size, void* d_ws, size_t ws_size,
                              hipStream_t stream) {
    const float* x       = (const float*)d_in[0];
    const float* pre_w   = (const float*)d_in[1];
    const float* pre_b   = (const float*)d_in[2];
    const float* weights = (const float*)d_in[3];
    const float* fc_w    = (const float*)d_in[4];
    const float* fc_b    = (const float*)d_in[5];
    const float* gamma   = (const float*)d_in[6];
    const float* beta    = (const float*)d_in[7];

    float* partial = (float*)d_ws;           // NBLK1*8*4 = 64 KB

    hipLaunchKernelGGL(fused_kernel, dim3(NBLK1), dim3(256), 0, stream,
                       x, pre_w, pre_b, weights, fc_w, fc_b,
                       (float4*)d_out, partial);
    hipLaunchKernelGGL(finalize_kernel, dim3(NB / 256), dim3(256), 0, stream,
                       (float4*)d_out, partial, gamma, beta);
}